// Round 1
// baseline (415.169 us; speedup 1.0000x reference)
//
#include <hip/hip_runtime.h>
#include <hip/hip_bf16.h>

#define NN 50000
#define NEDGE 800000
#define INDIM 256
#define NH 8
#define ND 32
#define HD 256
#define NT 4
#define NF 16

__device__ __forceinline__ float bf2f(unsigned short u) {
    return __uint_as_float(((unsigned int)u) << 16);
}

// ---------------- GEMM: feat[N,256] @ W[256,256] -> fs (bf16) [N,256]
__global__ __launch_bounds__(256) void gemm_kernel(
    const float* __restrict__ feat, const float* __restrict__ W,
    __hip_bfloat16* __restrict__ fs, int nrows)
{
    __shared__ float ftile[32][INDIM];   // 32 KB
    const int block_row = blockIdx.x * 32;
    const int tid = threadIdx.x;
    // stage 32x256 floats, coalesced float4
    for (int i = tid; i < 32 * 64; i += 256) {
        int r = i >> 6;
        int c4 = (i & 63) << 2;
        int row = block_row + r;
        float4 v = make_float4(0.f, 0.f, 0.f, 0.f);
        if (row < nrows)
            v = *reinterpret_cast<const float4*>(&feat[(size_t)row * INDIM + c4]);
        *reinterpret_cast<float4*>(&ftile[r][c4]) = v;
    }
    __syncthreads();

    const int cx = tid & 63;   // 64 column groups of 4 cols
    const int ry = tid >> 6;   // 4 row groups of 8 rows
    const int c0 = cx * 4;
    const int r0 = ry * 8;

    float acc[8][4];
    #pragma unroll
    for (int r = 0; r < 8; ++r)
        #pragma unroll
        for (int c = 0; c < 4; ++c) acc[r][c] = 0.f;

    for (int k = 0; k < INDIM; k += 4) {
        float4 w0 = *reinterpret_cast<const float4*>(&W[(size_t)(k + 0) * HD + c0]);
        float4 w1 = *reinterpret_cast<const float4*>(&W[(size_t)(k + 1) * HD + c0]);
        float4 w2 = *reinterpret_cast<const float4*>(&W[(size_t)(k + 2) * HD + c0]);
        float4 w3 = *reinterpret_cast<const float4*>(&W[(size_t)(k + 3) * HD + c0]);
        #pragma unroll
        for (int r = 0; r < 8; ++r) {
            float4 a = *reinterpret_cast<const float4*>(&ftile[r0 + r][k]);
            acc[r][0] = fmaf(a.x, w0.x, fmaf(a.y, w1.x, fmaf(a.z, w2.x, fmaf(a.w, w3.x, acc[r][0]))));
            acc[r][1] = fmaf(a.x, w0.y, fmaf(a.y, w1.y, fmaf(a.z, w2.y, fmaf(a.w, w3.y, acc[r][1]))));
            acc[r][2] = fmaf(a.x, w0.z, fmaf(a.y, w1.z, fmaf(a.z, w2.z, fmaf(a.w, w3.z, acc[r][2]))));
            acc[r][3] = fmaf(a.x, w0.w, fmaf(a.y, w1.w, fmaf(a.z, w2.w, fmaf(a.w, w3.w, acc[r][3]))));
        }
    }

    #pragma unroll
    for (int r = 0; r < 8; ++r) {
        int row = block_row + r0 + r;
        if (row < nrows) {
            union { ushort4 u4; __hip_bfloat16 h[4]; } cvt;
            #pragma unroll
            for (int c = 0; c < 4; ++c) cvt.h[c] = __float2bfloat16(acc[r][c]);
            *reinterpret_cast<ushort4*>(&fs[(size_t)row * HD + c0]) = cvt.u4;
        }
    }
}

// ---------------- el/er: [N,H,T] = einsum(fs[n,h,d], attn_{l,r}[h,d,t])
__global__ __launch_bounds__(256) void elr_kernel(
    const __hip_bfloat16* __restrict__ fs,
    const float* __restrict__ attn_l, const float* __restrict__ attn_r,
    float* __restrict__ el, float* __restrict__ er, int n)
{
    __shared__ float s_al[NH * ND * NT];
    __shared__ float s_ar[NH * ND * NT];
    for (int i = threadIdx.x; i < NH * ND * NT; i += 256) {
        s_al[i] = attn_l[i];
        s_ar[i] = attn_r[i];
    }
    __syncthreads();
    int wv = threadIdx.x >> 6, lane = threadIdx.x & 63;
    int node = blockIdx.x * 4 + wv;
    if (node >= n) return;
    int h = lane >> 3, j0 = (lane & 7) * 4;   // this lane covers d = j0..j0+3 of head h
    ushort4 u = *reinterpret_cast<const ushort4*>(fs + (size_t)node * HD + lane * 4);
    float f0 = bf2f(u.x), f1 = bf2f(u.y), f2 = bf2f(u.z), f3 = bf2f(u.w);
    const float* al = s_al + h * (ND * NT) + j0 * NT;
    const float* ar = s_ar + h * (ND * NT) + j0 * NT;
    float pl[NT], pr[NT];
    #pragma unroll
    for (int t = 0; t < NT; ++t) {
        pl[t] = f0*al[t] + f1*al[NT + t] + f2*al[2*NT + t] + f3*al[3*NT + t];
        pr[t] = f0*ar[t] + f1*ar[NT + t] + f2*ar[2*NT + t] + f3*ar[3*NT + t];
    }
    #pragma unroll
    for (int d = 1; d < 8; d <<= 1) {
        #pragma unroll
        for (int t = 0; t < NT; ++t) {
            pl[t] += __shfl_xor(pl[t], d);
            pr[t] += __shfl_xor(pr[t], d);
        }
    }
    if ((lane & 7) == 0) {
        #pragma unroll
        for (int t = 0; t < NT; ++t) {
            el[(size_t)node * (NH*NT) + h * NT + t] = pl[t];
            er[(size_t)node * (NH*NT) + h * NT + t] = pr[t];
        }
    }
}

// ---------------- per-edge logits -> eAtt [E,H] (after mask dot, /3, leaky relu)
__global__ __launch_bounds__(256) void edge_kernel(
    const float* __restrict__ e_pro, const float* __restrict__ mask,
    const float* __restrict__ attn_m, const int* __restrict__ src,
    const int* __restrict__ dst, const float* __restrict__ el,
    const float* __restrict__ er, float* __restrict__ eAtt, int ne)
{
    __shared__ float s_am[NH * NF * NT];   // 512 floats
    for (int i = threadIdx.x; i < NH * NF * NT; i += 256) s_am[i] = attn_m[i];
    __syncthreads();
    int e = blockIdx.x * 256 + threadIdx.x;
    if (e >= ne) return;
    float epf[NF];
    #pragma unroll
    for (int j = 0; j < 4; ++j) {
        float4 v = *reinterpret_cast<const float4*>(&e_pro[(size_t)e * NF + j * 4]);
        epf[j*4+0] = v.x; epf[j*4+1] = v.y; epf[j*4+2] = v.z; epf[j*4+3] = v.w;
    }
    float4 mk = *reinterpret_cast<const float4*>(&mask[(size_t)e * NT]);
    int s = src[e], d = dst[e];
    const float* elp = el + (size_t)s * (NH*NT);
    const float* erp = er + (size_t)d * (NH*NT);
    float out[NH];
    #pragma unroll
    for (int h = 0; h < NH; ++h) {
        float em0 = 0.f, em1 = 0.f, em2 = 0.f, em3 = 0.f;
        const float* am = s_am + h * (NF * NT);
        #pragma unroll
        for (int f = 0; f < NF; ++f) {
            float v = epf[f];
            em0 = fmaf(v, am[f*4+0], em0);
            em1 = fmaf(v, am[f*4+1], em1);
            em2 = fmaf(v, am[f*4+2], em2);
            em3 = fmaf(v, am[f*4+3], em3);
        }
        float4 lv = *reinterpret_cast<const float4*>(elp + h * 4);
        float4 rv = *reinterpret_cast<const float4*>(erp + h * 4);
        float sum = (lv.x + rv.x + em0) * mk.x
                  + (lv.y + rv.y + em1) * mk.y
                  + (lv.z + rv.z + em2) * mk.z
                  + (lv.w + rv.w + em3) * mk.w;
        sum *= (1.0f / 3.0f);
        out[h] = sum > 0.f ? sum : 0.2f * sum;
    }
    float4* op = reinterpret_cast<float4*>(&eAtt[(size_t)e * NH]);
    op[0] = make_float4(out[0], out[1], out[2], out[3]);
    op[1] = make_float4(out[4], out[5], out[6], out[7]);
}

// ---------------- CSR build
__global__ void init_kernel(int* cnt, int* cursor, int n) {
    int i = blockIdx.x * 256 + threadIdx.x;
    if (i < n) { cnt[i] = 0; cursor[i] = 0; }
}

__global__ void hist_kernel(const int* __restrict__ dst, int* __restrict__ cnt, int ne) {
    int e = blockIdx.x * 256 + threadIdx.x;
    if (e < ne) atomicAdd(&cnt[dst[e]], 1);
}

__global__ void scan1_kernel(const int* __restrict__ cnt, int* __restrict__ off,
                             int* __restrict__ blksum, int n) {
    __shared__ int sm[256];
    int i = blockIdx.x * 256 + threadIdx.x;
    int v = (i < n) ? cnt[i] : 0;
    sm[threadIdx.x] = v;
    __syncthreads();
    for (int d = 1; d < 256; d <<= 1) {
        int t = (threadIdx.x >= d) ? sm[threadIdx.x - d] : 0;
        __syncthreads();
        sm[threadIdx.x] += t;
        __syncthreads();
    }
    if (i < n) off[i] = sm[threadIdx.x] - v;   // exclusive
    if (threadIdx.x == 255) blksum[blockIdx.x] = sm[255];
}

__global__ void scan2_kernel(int* blksum, int nb) {
    __shared__ int sm[256];
    int v = (threadIdx.x < nb) ? blksum[threadIdx.x] : 0;
    sm[threadIdx.x] = v;
    __syncthreads();
    for (int d = 1; d < 256; d <<= 1) {
        int t = (threadIdx.x >= d) ? sm[threadIdx.x - d] : 0;
        __syncthreads();
        sm[threadIdx.x] += t;
        __syncthreads();
    }
    blksum[threadIdx.x] = sm[threadIdx.x] - v;  // exclusive
}

__global__ void scan3_kernel(int* __restrict__ off, const int* __restrict__ blksum,
                             int n, int ne) {
    int i = blockIdx.x * 256 + threadIdx.x;
    if (i < n) off[i] += blksum[blockIdx.x];
    if (i == 0) off[n] = ne;
}

__global__ void fill_kernel(const int* __restrict__ dst, const int* __restrict__ off,
                            int* __restrict__ cursor, int* __restrict__ csr, int ne) {
    int e = blockIdx.x * 256 + threadIdx.x;
    if (e < ne) {
        int d = dst[e];
        int p = atomicAdd(&cursor[d], 1);
        csr[off[d] + p] = e;
    }
}

// ---------------- fused edge-softmax + aggregation, one wave per dst node
__global__ __launch_bounds__(256) void agg_kernel(
    const int* __restrict__ off, const int* __restrict__ csr,
    const int* __restrict__ src, const float* __restrict__ eAtt,
    const __hip_bfloat16* __restrict__ fs, float* __restrict__ out, int n)
{
    int wv = threadIdx.x >> 6, lane = threadIdx.x & 63;
    int node = blockIdx.x * 4 + wv;
    if (node >= n) return;
    int beg = off[node], end = off[node + 1];

    // phase A: online (max, sum-of-exp) per head; lane handles head (lane&7),
    // edge sub-stream (lane>>3)
    int h1 = lane & 7;
    float m = -INFINITY, s = 0.f;
    for (int i = beg + (lane >> 3); i < end; i += 8) {
        int e = csr[i];
        float v = eAtt[(size_t)e * NH + h1];
        if (v > m) { s = s * __expf(m - v) + 1.f; m = v; }
        else        s += __expf(v - m);
    }
    #pragma unroll
    for (int d = 8; d < 64; d <<= 1) {
        float mo = __shfl_xor(m, d);
        float so = __shfl_xor(s, d);
        if (mo > m)      { s = s * __expf(m - mo) + so; m = mo; }
        else if (so > 0.f) s += so * __expf(mo - m);
    }

    // phase B: lane owns output cols lane*4..lane*4+3 (head = lane>>3)
    int h2 = lane >> 3;
    float M = __shfl(m, h2);    // lane h2 (0..7) holds stats for head h2
    float S = __shfl(s, h2);
    float invS = S > 0.f ? 1.f / S : 0.f;
    float a0 = 0.f, a1 = 0.f, a2 = 0.f, a3 = 0.f;
    const int col = lane * 4;
    for (int i = beg; i < end; ++i) {
        int e = csr[i];
        int sn = src[e];
        float v = eAtt[(size_t)e * NH + h2];
        float a = __expf(v - M) * invS;
        ushort4 u = *reinterpret_cast<const ushort4*>(fs + (size_t)sn * HD + col);
        a0 = fmaf(a, bf2f(u.x), a0);
        a1 = fmaf(a, bf2f(u.y), a1);
        a2 = fmaf(a, bf2f(u.z), a2);
        a3 = fmaf(a, bf2f(u.w), a3);
    }
    *reinterpret_cast<float4*>(&out[(size_t)node * HD + col]) = make_float4(a0, a1, a2, a3);
}

extern "C" void kernel_launch(void* const* d_in, const int* in_sizes, int n_in,
                              void* d_out, int out_size, void* d_ws, size_t ws_size,
                              hipStream_t stream)
{
    const float* feat   = (const float*)d_in[0];
    const float* e_pro  = (const float*)d_in[1];
    const float* mask   = (const float*)d_in[2];
    const float* W_n    = (const float*)d_in[3];
    const float* attn_l = (const float*)d_in[4];
    const float* attn_r = (const float*)d_in[5];
    const float* attn_m = (const float*)d_in[6];
    const int* src      = (const int*)d_in[7];
    const int* dst      = (const int*)d_in[8];
    float* out = (float*)d_out;

    char* ws = (char*)d_ws;
    size_t o = 0;
    auto alloc = [&](size_t bytes) -> void* {
        void* p = (void*)(ws + o);
        o += (bytes + 255) & ~(size_t)255;
        return p;
    };
    __hip_bfloat16* fs = (__hip_bfloat16*)alloc((size_t)NN * HD * 2);
    float* el   = (float*)alloc((size_t)NN * NH * NT * 4);
    float* er   = (float*)alloc((size_t)NN * NH * NT * 4);
    float* eAtt = (float*)alloc((size_t)NEDGE * NH * 4);
    int* cnt    = (int*)alloc((size_t)NN * 4);
    int* cursor = (int*)alloc((size_t)NN * 4);
    int* offs   = (int*)alloc((size_t)(NN + 1) * 4);
    int* blksum = (int*)alloc(256 * 4);
    int* csr    = (int*)alloc((size_t)NEDGE * 4);
    (void)ws_size; (void)in_sizes; (void)n_in; (void)out_size;

    dim3 b256(256);
    hipLaunchKernelGGL(gemm_kernel, dim3((NN + 31) / 32), b256, 0, stream, feat, W_n, fs, NN);
    hipLaunchKernelGGL(elr_kernel, dim3((NN + 3) / 4), b256, 0, stream, fs, attn_l, attn_r, el, er, NN);
    hipLaunchKernelGGL(edge_kernel, dim3((NEDGE + 255) / 256), b256, 0, stream,
                       e_pro, mask, attn_m, src, dst, el, er, eAtt, NEDGE);
    hipLaunchKernelGGL(init_kernel, dim3((NN + 255) / 256), b256, 0, stream, cnt, cursor, NN);
    hipLaunchKernelGGL(hist_kernel, dim3((NEDGE + 255) / 256), b256, 0, stream, dst, cnt, NEDGE);
    hipLaunchKernelGGL(scan1_kernel, dim3((NN + 255) / 256), b256, 0, stream, cnt, offs, blksum, NN);
    hipLaunchKernelGGL(scan2_kernel, dim3(1), b256, 0, stream, blksum, (NN + 255) / 256);
    hipLaunchKernelGGL(scan3_kernel, dim3((NN + 255) / 256), b256, 0, stream, offs, blksum, NN, NEDGE);
    hipLaunchKernelGGL(fill_kernel, dim3((NEDGE + 255) / 256), b256, 0, stream, dst, offs, cursor, csr, NEDGE);
    hipLaunchKernelGGL(agg_kernel, dim3((NN + 3) / 4), b256, 0, stream, offs, csr, src, eAtt, fs, out, NN);
}

// Round 2
// 327.304 us; speedup vs baseline: 1.2685x; 1.2685x over previous
//
#include <hip/hip_runtime.h>
#include <hip/hip_bf16.h>

#define NN 50000
#define NEDGE 800000
#define INDIM 256
#define NH 8
#define ND 32
#define HD 256
#define NT 4
#define NF 16

typedef __attribute__((ext_vector_type(8))) short s16x8;
typedef __attribute__((ext_vector_type(4))) float f32x4;

__device__ __forceinline__ float bf2f(unsigned short u) {
    return __uint_as_float(((unsigned int)u) << 16);
}
__device__ __forceinline__ unsigned short f2bf(float f) {
    __hip_bfloat16 h = __float2bfloat16(f);
    return *reinterpret_cast<unsigned short*>(&h);
}

// ---------------- W transpose + bf16: W[k][c] f32 -> Wt[c][k] bf16
__global__ __launch_bounds__(256) void wt_kernel(const float* __restrict__ W,
                                                 unsigned short* __restrict__ Wt)
{
    int idx = blockIdx.x * 256 + threadIdx.x;   // 65536 total
    int k = idx >> 8, c = idx & 255;
    Wt[(size_t)c * 256 + k] = f2bf(W[idx]);
}

// ---------------- MFMA GEMM: feat[N,256]f32 @ W -> fs[N,256] bf16
// block = 4 waves; block computes 32 rows x 256 cols; wave w covers cols w*64..w*64+63
__global__ __launch_bounds__(256) void gemm_mfma(
    const float* __restrict__ feat, const unsigned short* __restrict__ Wt,
    unsigned short* __restrict__ fs, int nrows)
{
    const int wave = threadIdx.x >> 6, lane = threadIdx.x & 63;
    const int brow = blockIdx.x * 32;
    const int c0 = wave * 64;
    const int rA = lane & 15;       // A row within tile / B col within tile / C col
    const int kg = lane >> 4;       // k-group 0..3

    int r0 = brow + rA;
    int r1 = brow + 16 + rA;
    if (r0 >= nrows) r0 = nrows - 1;   // clamped lanes only feed unstored rows
    if (r1 >= nrows) r1 = nrows - 1;

    f32x4 acc[2][4] = {};

    for (int k0 = 0; k0 < 256; k0 += 32) {
        const int kk = k0 + kg * 8;
        const float* pa0 = feat + (size_t)r0 * 256 + kk;
        const float* pa1 = feat + (size_t)r1 * 256 + kk;
        float4 x0 = *reinterpret_cast<const float4*>(pa0);
        float4 x1 = *reinterpret_cast<const float4*>(pa0 + 4);
        float4 y0 = *reinterpret_cast<const float4*>(pa1);
        float4 y1 = *reinterpret_cast<const float4*>(pa1 + 4);
        s16x8 a0, a1;
        a0[0] = (short)f2bf(x0.x); a0[1] = (short)f2bf(x0.y);
        a0[2] = (short)f2bf(x0.z); a0[3] = (short)f2bf(x0.w);
        a0[4] = (short)f2bf(x1.x); a0[5] = (short)f2bf(x1.y);
        a0[6] = (short)f2bf(x1.z); a0[7] = (short)f2bf(x1.w);
        a1[0] = (short)f2bf(y0.x); a1[1] = (short)f2bf(y0.y);
        a1[2] = (short)f2bf(y0.z); a1[3] = (short)f2bf(y0.w);
        a1[4] = (short)f2bf(y1.x); a1[5] = (short)f2bf(y1.y);
        a1[6] = (short)f2bf(y1.z); a1[7] = (short)f2bf(y1.w);
        #pragma unroll
        for (int ct = 0; ct < 4; ++ct) {
            s16x8 b = *reinterpret_cast<const s16x8*>(Wt + (size_t)(c0 + ct * 16 + rA) * 256 + kk);
            acc[0][ct] = __builtin_amdgcn_mfma_f32_16x16x32_bf16(a0, b, acc[0][ct], 0, 0, 0);
            acc[1][ct] = __builtin_amdgcn_mfma_f32_16x16x32_bf16(a1, b, acc[1][ct], 0, 0, 0);
        }
    }

    // C: col = c0 + ct*16 + rA, row = brow + rt*16 + kg*4 + r
    #pragma unroll
    for (int rt = 0; rt < 2; ++rt) {
        #pragma unroll
        for (int r = 0; r < 4; ++r) {
            int row = brow + rt * 16 + kg * 4 + r;
            if (row < nrows) {
                #pragma unroll
                for (int ct = 0; ct < 4; ++ct) {
                    fs[(size_t)row * 256 + c0 + ct * 16 + rA] = f2bf(acc[rt][ct][r]);
                }
            }
        }
    }
}

// ---------------- el/er: [N,H,T] = einsum(fs[n,h,d], attn_{l,r}[h,d,t])
__global__ __launch_bounds__(256) void elr_kernel(
    const unsigned short* __restrict__ fs,
    const float* __restrict__ attn_l, const float* __restrict__ attn_r,
    float* __restrict__ el, float* __restrict__ er, int n)
{
    __shared__ float s_al[NH * ND * NT];
    __shared__ float s_ar[NH * ND * NT];
    for (int i = threadIdx.x; i < NH * ND * NT; i += 256) {
        s_al[i] = attn_l[i];
        s_ar[i] = attn_r[i];
    }
    __syncthreads();
    int wv = threadIdx.x >> 6, lane = threadIdx.x & 63;
    int node = blockIdx.x * 4 + wv;
    if (node >= n) return;
    int h = lane >> 3, j0 = (lane & 7) * 4;
    ushort4 u = *reinterpret_cast<const ushort4*>(fs + (size_t)node * HD + lane * 4);
    float f0 = bf2f(u.x), f1 = bf2f(u.y), f2 = bf2f(u.z), f3 = bf2f(u.w);
    const float* al = s_al + h * (ND * NT) + j0 * NT;
    const float* ar = s_ar + h * (ND * NT) + j0 * NT;
    float pl[NT], pr[NT];
    #pragma unroll
    for (int t = 0; t < NT; ++t) {
        pl[t] = f0*al[t] + f1*al[NT + t] + f2*al[2*NT + t] + f3*al[3*NT + t];
        pr[t] = f0*ar[t] + f1*ar[NT + t] + f2*ar[2*NT + t] + f3*ar[3*NT + t];
    }
    #pragma unroll
    for (int d = 1; d < 8; d <<= 1) {
        #pragma unroll
        for (int t = 0; t < NT; ++t) {
            pl[t] += __shfl_xor(pl[t], d);
            pr[t] += __shfl_xor(pr[t], d);
        }
    }
    if ((lane & 7) == 0) {
        #pragma unroll
        for (int t = 0; t < NT; ++t) {
            el[(size_t)node * (NH*NT) + h * NT + t] = pl[t];
            er[(size_t)node * (NH*NT) + h * NT + t] = pr[t];
        }
    }
}

// ---------------- per-edge logits -> eAtt [E,H]
__global__ __launch_bounds__(256) void edge_kernel(
    const float* __restrict__ e_pro, const float* __restrict__ mask,
    const float* __restrict__ attn_m, const int* __restrict__ src,
    const int* __restrict__ dst, const float* __restrict__ el,
    const float* __restrict__ er, float* __restrict__ eAtt, int ne)
{
    __shared__ float s_am[NH * NF * NT];
    for (int i = threadIdx.x; i < NH * NF * NT; i += 256) s_am[i] = attn_m[i];
    __syncthreads();
    int e = blockIdx.x * 256 + threadIdx.x;
    if (e >= ne) return;
    float epf[NF];
    #pragma unroll
    for (int j = 0; j < 4; ++j) {
        float4 v = *reinterpret_cast<const float4*>(&e_pro[(size_t)e * NF + j * 4]);
        epf[j*4+0] = v.x; epf[j*4+1] = v.y; epf[j*4+2] = v.z; epf[j*4+3] = v.w;
    }
    float4 mk = *reinterpret_cast<const float4*>(&mask[(size_t)e * NT]);
    int s = src[e], d = dst[e];
    const float* elp = el + (size_t)s * (NH*NT);
    const float* erp = er + (size_t)d * (NH*NT);
    float out[NH];
    #pragma unroll
    for (int h = 0; h < NH; ++h) {
        float em0 = 0.f, em1 = 0.f, em2 = 0.f, em3 = 0.f;
        const float* am = s_am + h * (NF * NT);
        #pragma unroll
        for (int f = 0; f < NF; ++f) {
            float v = epf[f];
            em0 = fmaf(v, am[f*4+0], em0);
            em1 = fmaf(v, am[f*4+1], em1);
            em2 = fmaf(v, am[f*4+2], em2);
            em3 = fmaf(v, am[f*4+3], em3);
        }
        float4 lv = *reinterpret_cast<const float4*>(elp + h * 4);
        float4 rv = *reinterpret_cast<const float4*>(erp + h * 4);
        float sum = (lv.x + rv.x + em0) * mk.x
                  + (lv.y + rv.y + em1) * mk.y
                  + (lv.z + rv.z + em2) * mk.z
                  + (lv.w + rv.w + em3) * mk.w;
        sum *= (1.0f / 3.0f);
        out[h] = sum > 0.f ? sum : 0.2f * sum;
    }
    float4* op = reinterpret_cast<float4*>(&eAtt[(size_t)e * NH]);
    op[0] = make_float4(out[0], out[1], out[2], out[3]);
    op[1] = make_float4(out[4], out[5], out[6], out[7]);
}

// ---------------- CSR build
__global__ void init_kernel(int* cnt, int* cursor, int n) {
    int i = blockIdx.x * 256 + threadIdx.x;
    if (i < n) { cnt[i] = 0; cursor[i] = 0; }
}

__global__ void hist_kernel(const int* __restrict__ dst, int* __restrict__ cnt, int ne) {
    int e = blockIdx.x * 256 + threadIdx.x;
    if (e < ne) atomicAdd(&cnt[dst[e]], 1);
}

__global__ void scan1_kernel(const int* __restrict__ cnt, int* __restrict__ off,
                             int* __restrict__ blksum, int n) {
    __shared__ int sm[256];
    int i = blockIdx.x * 256 + threadIdx.x;
    int v = (i < n) ? cnt[i] : 0;
    sm[threadIdx.x] = v;
    __syncthreads();
    for (int d = 1; d < 256; d <<= 1) {
        int t = (threadIdx.x >= d) ? sm[threadIdx.x - d] : 0;
        __syncthreads();
        sm[threadIdx.x] += t;
        __syncthreads();
    }
    if (i < n) off[i] = sm[threadIdx.x] - v;
    if (threadIdx.x == 255) blksum[blockIdx.x] = sm[255];
}

__global__ void scan2_kernel(int* blksum, int nb) {
    __shared__ int sm[256];
    int v = (threadIdx.x < nb) ? blksum[threadIdx.x] : 0;
    sm[threadIdx.x] = v;
    __syncthreads();
    for (int d = 1; d < 256; d <<= 1) {
        int t = (threadIdx.x >= d) ? sm[threadIdx.x - d] : 0;
        __syncthreads();
        sm[threadIdx.x] += t;
        __syncthreads();
    }
    blksum[threadIdx.x] = sm[threadIdx.x] - v;
}

__global__ void scan3_kernel(int* __restrict__ off, const int* __restrict__ blksum,
                             int n, int ne) {
    int i = blockIdx.x * 256 + threadIdx.x;
    if (i < n) off[i] += blksum[blockIdx.x];
    if (i == 0) off[n] = ne;
}

// fill: scatter src + eAtt row into slot-sorted arrays
__global__ void fill_kernel(const int* __restrict__ dst, const int* __restrict__ src,
                            const float* __restrict__ eAtt,
                            const int* __restrict__ off, int* __restrict__ cursor,
                            int* __restrict__ srcS, float* __restrict__ eS, int ne) {
    int e = blockIdx.x * 256 + threadIdx.x;
    if (e < ne) {
        int d = dst[e];
        int p = atomicAdd(&cursor[d], 1);
        int slot = off[d] + p;
        srcS[slot] = src[e];
        const float4* s4 = reinterpret_cast<const float4*>(eAtt + (size_t)e * NH);
        float4 v0 = s4[0], v1 = s4[1];
        float4* d4 = reinterpret_cast<float4*>(eS + (size_t)slot * NH);
        d4[0] = v0; d4[1] = v1;
    }
}

// ---------------- stats: per node compute per-head (max, sum), rewrite eS in place as alpha
__global__ __launch_bounds__(256) void stats_kernel(
    const int* __restrict__ off, float* __restrict__ eS, int n)
{
    int wv = threadIdx.x >> 6, lane = threadIdx.x & 63;
    int node = blockIdx.x * 4 + wv;
    if (node >= n) return;
    int beg = off[node], end = off[node + 1];
    int h = lane & 7, sub = lane >> 3;
    float m = -INFINITY, s = 0.f;
    for (int i = beg + sub; i < end; i += 8) {
        float v = eS[(size_t)i * NH + h];
        if (v > m) { s = s * __expf(m - v) + 1.f; m = v; }
        else         s += __expf(v - m);
    }
    #pragma unroll
    for (int d = 8; d < 64; d <<= 1) {
        float mo = __shfl_xor(m, d);
        float so = __shfl_xor(s, d);
        if (mo > m)        { s = s * __expf(m - mo) + so; m = mo; }
        else if (so > 0.f)   s += so * __expf(mo - m);
    }
    float invS = s > 0.f ? 1.f / s : 0.f;
    for (int i = beg + sub; i < end; i += 8) {
        size_t idx = (size_t)i * NH + h;
        float v = eS[idx];
        eS[idx] = __expf(v - m) * invS;
    }
}

// ---------------- aggregation: one wave per dst node, single gather level
__global__ __launch_bounds__(256) void agg_kernel(
    const int* __restrict__ off, const int* __restrict__ srcS,
    const float* __restrict__ alpha, const unsigned short* __restrict__ fs,
    float* __restrict__ out, int n)
{
    int wv = threadIdx.x >> 6, lane = threadIdx.x & 63;
    int node = blockIdx.x * 4 + wv;
    if (node >= n) return;
    int beg = off[node], end = off[node + 1];
    const int h2 = lane >> 3;
    const int col = lane * 4;
    float a0 = 0.f, a1 = 0.f, a2 = 0.f, a3 = 0.f;
    int i = beg;
    for (; i + 3 < end; i += 4) {
        int s0 = srcS[i], s1 = srcS[i+1], s2 = srcS[i+2], s3 = srcS[i+3];
        float w0 = alpha[(size_t)(i  ) * NH + h2];
        float w1 = alpha[(size_t)(i+1) * NH + h2];
        float w2 = alpha[(size_t)(i+2) * NH + h2];
        float w3 = alpha[(size_t)(i+3) * NH + h2];
        ushort4 u0 = *reinterpret_cast<const ushort4*>(fs + (size_t)s0 * HD + col);
        ushort4 u1 = *reinterpret_cast<const ushort4*>(fs + (size_t)s1 * HD + col);
        ushort4 u2 = *reinterpret_cast<const ushort4*>(fs + (size_t)s2 * HD + col);
        ushort4 u3 = *reinterpret_cast<const ushort4*>(fs + (size_t)s3 * HD + col);
        a0 = fmaf(w0, bf2f(u0.x), a0); a1 = fmaf(w0, bf2f(u0.y), a1);
        a2 = fmaf(w0, bf2f(u0.z), a2); a3 = fmaf(w0, bf2f(u0.w), a3);
        a0 = fmaf(w1, bf2f(u1.x), a0); a1 = fmaf(w1, bf2f(u1.y), a1);
        a2 = fmaf(w1, bf2f(u1.z), a2); a3 = fmaf(w1, bf2f(u1.w), a3);
        a0 = fmaf(w2, bf2f(u2.x), a0); a1 = fmaf(w2, bf2f(u2.y), a1);
        a2 = fmaf(w2, bf2f(u2.z), a2); a3 = fmaf(w2, bf2f(u2.w), a3);
        a0 = fmaf(w3, bf2f(u3.x), a0); a1 = fmaf(w3, bf2f(u3.y), a1);
        a2 = fmaf(w3, bf2f(u3.z), a2); a3 = fmaf(w3, bf2f(u3.w), a3);
    }
    for (; i < end; ++i) {
        int sn = srcS[i];
        float w = alpha[(size_t)i * NH + h2];
        ushort4 u = *reinterpret_cast<const ushort4*>(fs + (size_t)sn * HD + col);
        a0 = fmaf(w, bf2f(u.x), a0); a1 = fmaf(w, bf2f(u.y), a1);
        a2 = fmaf(w, bf2f(u.z), a2); a3 = fmaf(w, bf2f(u.w), a3);
    }
    *reinterpret_cast<float4*>(&out[(size_t)node * HD + col]) = make_float4(a0, a1, a2, a3);
}

extern "C" void kernel_launch(void* const* d_in, const int* in_sizes, int n_in,
                              void* d_out, int out_size, void* d_ws, size_t ws_size,
                              hipStream_t stream)
{
    const float* feat   = (const float*)d_in[0];
    const float* e_pro  = (const float*)d_in[1];
    const float* mask   = (const float*)d_in[2];
    const float* W_n    = (const float*)d_in[3];
    const float* attn_l = (const float*)d_in[4];
    const float* attn_r = (const float*)d_in[5];
    const float* attn_m = (const float*)d_in[6];
    const int* src      = (const int*)d_in[7];
    const int* dst      = (const int*)d_in[8];
    float* out = (float*)d_out;

    char* ws = (char*)d_ws;
    size_t o = 0;
    auto alloc = [&](size_t bytes) -> void* {
        void* p = (void*)(ws + o);
        o += (bytes + 255) & ~(size_t)255;
        return p;
    };
    unsigned short* fs  = (unsigned short*)alloc((size_t)NN * HD * 2);
    unsigned short* Wt  = (unsigned short*)alloc((size_t)INDIM * HD * 2);
    float* el   = (float*)alloc((size_t)NN * NH * NT * 4);
    float* er   = (float*)alloc((size_t)NN * NH * NT * 4);
    float* eAtt = (float*)alloc((size_t)NEDGE * NH * 4);
    float* eS   = (float*)alloc((size_t)NEDGE * NH * 4);   // sorted logits -> alpha (in place)
    int* srcS   = (int*)alloc((size_t)NEDGE * 4);
    int* cnt    = (int*)alloc((size_t)NN * 4);
    int* cursor = (int*)alloc((size_t)NN * 4);
    int* offs   = (int*)alloc((size_t)(NN + 1) * 4);
    int* blksum = (int*)alloc(256 * 4);
    (void)ws_size; (void)in_sizes; (void)n_in; (void)out_size;

    dim3 b256(256);
    hipLaunchKernelGGL(wt_kernel, dim3(256), b256, 0, stream, W_n, Wt);
    hipLaunchKernelGGL(gemm_mfma, dim3((NN + 31) / 32), b256, 0, stream, feat, Wt, fs, NN);
    hipLaunchKernelGGL(elr_kernel, dim3((NN + 3) / 4), b256, 0, stream, fs, attn_l, attn_r, el, er, NN);
    hipLaunchKernelGGL(edge_kernel, dim3((NEDGE + 255) / 256), b256, 0, stream,
                       e_pro, mask, attn_m, src, dst, el, er, eAtt, NEDGE);
    hipLaunchKernelGGL(init_kernel, dim3((NN + 255) / 256), b256, 0, stream, cnt, cursor, NN);
    hipLaunchKernelGGL(hist_kernel, dim3((NEDGE + 255) / 256), b256, 0, stream, dst, cnt, NEDGE);
    hipLaunchKernelGGL(scan1_kernel, dim3((NN + 255) / 256), b256, 0, stream, cnt, offs, blksum, NN);
    hipLaunchKernelGGL(scan2_kernel, dim3(1), b256, 0, stream, blksum, (NN + 255) / 256);
    hipLaunchKernelGGL(scan3_kernel, dim3((NN + 255) / 256), b256, 0, stream, offs, blksum, NN, NEDGE);
    hipLaunchKernelGGL(fill_kernel, dim3((NEDGE + 255) / 256), b256, 0, stream,
                       dst, src, eAtt, offs, cursor, srcS, eS, NEDGE);
    hipLaunchKernelGGL(stats_kernel, dim3((NN + 3) / 4), b256, 0, stream, offs, eS, NN);
    hipLaunchKernelGGL(agg_kernel, dim3((NN + 3) / 4), b256, 0, stream, offs, srcS, eS, fs, out, NN);
}

// Round 3
// 270.318 us; speedup vs baseline: 1.5359x; 1.2108x over previous
//
#include <hip/hip_runtime.h>
#include <hip/hip_bf16.h>
#include <hip/hip_fp16.h>

#define NN 50000
#define NEDGE 800000
#define INDIM 256
#define NH 8
#define ND 32
#define HD 256
#define NT 4
#define NF 16

typedef __attribute__((ext_vector_type(8))) short s16x8;
typedef __attribute__((ext_vector_type(4))) float f32x4;
typedef unsigned short u16;

__device__ __forceinline__ float bf2f(u16 u) {
    return __uint_as_float(((unsigned int)u) << 16);
}
__device__ __forceinline__ u16 f2bf(float f) {
    __hip_bfloat16 h = __float2bfloat16(f);
    return *reinterpret_cast<u16*>(&h);
}
__device__ __forceinline__ u16 f2h(float f) {
    __half h = __float2half(f);
    return *reinterpret_cast<u16*>(&h);
}
__device__ __forceinline__ float h2f(u16 u) {
    __half h = *reinterpret_cast<__half*>(&u);
    return __half2float(h);
}

// ---------------- W transpose + bf16: W[k][c] f32 -> Wt[c][k] bf16
__global__ __launch_bounds__(256) void wt_kernel(const float* __restrict__ W,
                                                 u16* __restrict__ Wt)
{
    int idx = blockIdx.x * 256 + threadIdx.x;   // 65536 total
    int k = idx >> 8, c = idx & 255;
    Wt[(size_t)c * 256 + k] = f2bf(W[idx]);
}

// ---------------- MFMA GEMM: feat[N,256]f32 @ W -> fs[N,256] bf16
__global__ __launch_bounds__(256) void gemm_mfma(
    const float* __restrict__ feat, const u16* __restrict__ Wt,
    u16* __restrict__ fs, int nrows)
{
    const int wave = threadIdx.x >> 6, lane = threadIdx.x & 63;
    const int brow = blockIdx.x * 32;
    const int c0 = wave * 64;
    const int rA = lane & 15;
    const int kg = lane >> 4;

    int r0 = brow + rA;
    int r1 = brow + 16 + rA;
    if (r0 >= nrows) r0 = nrows - 1;
    if (r1 >= nrows) r1 = nrows - 1;

    f32x4 acc[2][4] = {};

    for (int k0 = 0; k0 < 256; k0 += 32) {
        const int kk = k0 + kg * 8;
        const float* pa0 = feat + (size_t)r0 * 256 + kk;
        const float* pa1 = feat + (size_t)r1 * 256 + kk;
        float4 x0 = *reinterpret_cast<const float4*>(pa0);
        float4 x1 = *reinterpret_cast<const float4*>(pa0 + 4);
        float4 y0 = *reinterpret_cast<const float4*>(pa1);
        float4 y1 = *reinterpret_cast<const float4*>(pa1 + 4);
        s16x8 a0, a1;
        a0[0] = (short)f2bf(x0.x); a0[1] = (short)f2bf(x0.y);
        a0[2] = (short)f2bf(x0.z); a0[3] = (short)f2bf(x0.w);
        a0[4] = (short)f2bf(x1.x); a0[5] = (short)f2bf(x1.y);
        a0[6] = (short)f2bf(x1.z); a0[7] = (short)f2bf(x1.w);
        a1[0] = (short)f2bf(y0.x); a1[1] = (short)f2bf(y0.y);
        a1[2] = (short)f2bf(y0.z); a1[3] = (short)f2bf(y0.w);
        a1[4] = (short)f2bf(y1.x); a1[5] = (short)f2bf(y1.y);
        a1[6] = (short)f2bf(y1.z); a1[7] = (short)f2bf(y1.w);
        #pragma unroll
        for (int ct = 0; ct < 4; ++ct) {
            s16x8 b = *reinterpret_cast<const s16x8*>(Wt + (size_t)(c0 + ct * 16 + rA) * 256 + kk);
            acc[0][ct] = __builtin_amdgcn_mfma_f32_16x16x32_bf16(a0, b, acc[0][ct], 0, 0, 0);
            acc[1][ct] = __builtin_amdgcn_mfma_f32_16x16x32_bf16(a1, b, acc[1][ct], 0, 0, 0);
        }
    }

    #pragma unroll
    for (int rt = 0; rt < 2; ++rt) {
        #pragma unroll
        for (int r = 0; r < 4; ++r) {
            int row = brow + rt * 16 + kg * 4 + r;
            if (row < nrows) {
                #pragma unroll
                for (int ct = 0; ct < 4; ++ct) {
                    fs[(size_t)row * 256 + c0 + ct * 16 + rA] = f2bf(acc[rt][ct][r]);
                }
            }
        }
    }
}

// ---------------- el/er (f16): [N,H,T] = einsum(fs[n,h,d], attn_{l,r}[h,d,t])
__global__ __launch_bounds__(256) void elr_kernel(
    const u16* __restrict__ fs,
    const float* __restrict__ attn_l, const float* __restrict__ attn_r,
    u16* __restrict__ el, u16* __restrict__ er, int n)
{
    __shared__ float s_al[NH * ND * NT];
    __shared__ float s_ar[NH * ND * NT];
    for (int i = threadIdx.x; i < NH * ND * NT; i += 256) {
        s_al[i] = attn_l[i];
        s_ar[i] = attn_r[i];
    }
    __syncthreads();
    int wv = threadIdx.x >> 6, lane = threadIdx.x & 63;
    int node = blockIdx.x * 4 + wv;
    if (node >= n) return;
    int h = lane >> 3, j0 = (lane & 7) * 4;
    ushort4 u = *reinterpret_cast<const ushort4*>(fs + (size_t)node * HD + lane * 4);
    float f0 = bf2f(u.x), f1 = bf2f(u.y), f2 = bf2f(u.z), f3 = bf2f(u.w);
    const float* al = s_al + h * (ND * NT) + j0 * NT;
    const float* ar = s_ar + h * (ND * NT) + j0 * NT;
    float pl[NT], pr[NT];
    #pragma unroll
    for (int t = 0; t < NT; ++t) {
        pl[t] = f0*al[t] + f1*al[NT + t] + f2*al[2*NT + t] + f3*al[3*NT + t];
        pr[t] = f0*ar[t] + f1*ar[NT + t] + f2*ar[2*NT + t] + f3*ar[3*NT + t];
    }
    #pragma unroll
    for (int d = 1; d < 8; d <<= 1) {
        #pragma unroll
        for (int t = 0; t < NT; ++t) {
            pl[t] += __shfl_xor(pl[t], d);
            pr[t] += __shfl_xor(pr[t], d);
        }
    }
    if ((lane & 7) == 0) {
        ushort4 ol, orr;
        ol.x = f2h(pl[0]); ol.y = f2h(pl[1]); ol.z = f2h(pl[2]); ol.w = f2h(pl[3]);
        orr.x = f2h(pr[0]); orr.y = f2h(pr[1]); orr.z = f2h(pr[2]); orr.w = f2h(pr[3]);
        *reinterpret_cast<ushort4*>(el + (size_t)node * (NH*NT) + h * NT) = ol;
        *reinterpret_cast<ushort4*>(er + (size_t)node * (NH*NT) + h * NT) = orr;
    }
}

// ---------------- CSR build
__global__ void init_kernel(int* cnt, int* cursor, int n) {
    int i = blockIdx.x * 256 + threadIdx.x;
    if (i < n) { cnt[i] = 0; cursor[i] = 0; }
}

__global__ void hist_kernel(const int* __restrict__ dst, int* __restrict__ cnt, int ne) {
    int e = blockIdx.x * 256 + threadIdx.x;
    if (e < ne) atomicAdd(&cnt[dst[e]], 1);
}

__global__ void scan1_kernel(const int* __restrict__ cnt, int* __restrict__ off,
                             int* __restrict__ blksum, int n) {
    __shared__ int sm[256];
    int i = blockIdx.x * 256 + threadIdx.x;
    int v = (i < n) ? cnt[i] : 0;
    sm[threadIdx.x] = v;
    __syncthreads();
    for (int d = 1; d < 256; d <<= 1) {
        int t = (threadIdx.x >= d) ? sm[threadIdx.x - d] : 0;
        __syncthreads();
        sm[threadIdx.x] += t;
        __syncthreads();
    }
    if (i < n) off[i] = sm[threadIdx.x] - v;
    if (threadIdx.x == 255) blksum[blockIdx.x] = sm[255];
}

__global__ void scan2_kernel(int* blksum, int nb) {
    __shared__ int sm[256];
    int v = (threadIdx.x < nb) ? blksum[threadIdx.x] : 0;
    sm[threadIdx.x] = v;
    __syncthreads();
    for (int d = 1; d < 256; d <<= 1) {
        int t = (threadIdx.x >= d) ? sm[threadIdx.x - d] : 0;
        __syncthreads();
        sm[threadIdx.x] += t;
        __syncthreads();
    }
    blksum[threadIdx.x] = sm[threadIdx.x] - v;
}

__global__ void scan3_kernel(int* __restrict__ off, const int* __restrict__ blksum,
                             int n, int ne) {
    int i = blockIdx.x * 256 + threadIdx.x;
    if (i < n) off[i] += blksum[blockIdx.x];
    if (i == 0) off[n] = ne;
}

// ---------------- fused edge logits + scatter to dst-sorted slots
// 8 lanes per edge; lane j handles head j. 32 edges per 256-thread block.
__global__ __launch_bounds__(256) void edgefill_kernel(
    const float* __restrict__ e_pro, const float* __restrict__ mask,
    const float* __restrict__ attn_m,
    const int* __restrict__ src, const int* __restrict__ dst,
    const u16* __restrict__ el, const u16* __restrict__ er,
    const int* __restrict__ off, int* __restrict__ cursor,
    int* __restrict__ srcS, float* __restrict__ eS, int ne)
{
    __shared__ float s_amT[NF * NT * NH];   // [f][t][h], conflict-free for lane j=h
    for (int i = threadIdx.x; i < NH * NF * NT; i += 256) {
        int h = i >> 6, f = (i >> 2) & 15, t = i & 3;   // i = h*64 + f*4 + t
        s_amT[(f * NT + t) * NH + h] = attn_m[i];
    }
    __syncthreads();

    int e = blockIdx.x * 32 + (threadIdx.x >> 3);
    if (e >= ne) return;
    const int lane = threadIdx.x & 63;
    const int j = threadIdx.x & 7;      // head

    int s = src[e], d = dst[e];
    float4 mk = *reinterpret_cast<const float4*>(mask + (size_t)e * NT);

    // this lane's head slice of el[src], er[dst]: 4 f16 = 8B
    union { uint2 v; u16 u[4]; } lv, rv;
    lv.v = *reinterpret_cast<const uint2*>(el + (size_t)s * (NH*NT) + j * NT);
    rv.v = *reinterpret_cast<const uint2*>(er + (size_t)d * (NH*NT) + j * NT);

    float epf[NF];
    #pragma unroll
    for (int q = 0; q < 4; ++q) {
        float4 v = *reinterpret_cast<const float4*>(e_pro + (size_t)e * NF + q * 4);
        epf[q*4+0] = v.x; epf[q*4+1] = v.y; epf[q*4+2] = v.z; epf[q*4+3] = v.w;
    }

    float em = 0.f;
    #pragma unroll
    for (int f = 0; f < NF; ++f) {
        float am = mk.x * s_amT[(f*NT + 0) * NH + j]
                 + mk.y * s_amT[(f*NT + 1) * NH + j]
                 + mk.z * s_amT[(f*NT + 2) * NH + j]
                 + mk.w * s_amT[(f*NT + 3) * NH + j];
        em = fmaf(epf[f], am, em);
    }
    float left  = mk.x*h2f(lv.u[0]) + mk.y*h2f(lv.u[1]) + mk.z*h2f(lv.u[2]) + mk.w*h2f(lv.u[3]);
    float right = mk.x*h2f(rv.u[0]) + mk.y*h2f(rv.u[1]) + mk.z*h2f(rv.u[2]) + mk.w*h2f(rv.u[3]);

    float val = (left + right + em) * (1.0f / 3.0f);
    val = val > 0.f ? val : 0.2f * val;

    int slot;
    if (j == 0) slot = off[d] + atomicAdd(&cursor[d], 1);
    slot = __shfl(slot, lane & 56);

    eS[(size_t)slot * NH + j] = val;
    if (j == 0) srcS[slot] = s;
}

// ---------------- fused edge-softmax stats + aggregation, one wave per dst node
__global__ __launch_bounds__(256) void agg_kernel(
    const int* __restrict__ off, const int* __restrict__ srcS,
    const float* __restrict__ eS, const u16* __restrict__ fs,
    float* __restrict__ out, int n)
{
    int wv = threadIdx.x >> 6, lane = threadIdx.x & 63;
    int node = blockIdx.x * 4 + wv;
    if (node >= n) return;
    int beg = off[node], end = off[node + 1];

    // phase A: per-head online (max, sum); lane = (sub<<3)|h
    int h = lane & 7, sub = lane >> 3;
    float m = -INFINITY, s = 0.f;
    for (int i = beg + sub; i < end; i += 8) {
        float v = eS[(size_t)i * NH + h];
        if (v > m) { s = s * __expf(m - v) + 1.f; m = v; }
        else         s += __expf(v - m);
    }
    #pragma unroll
    for (int d = 8; d < 64; d <<= 1) {
        float mo = __shfl_xor(m, d);
        float so = __shfl_xor(s, d);
        if (mo > m)        { s = s * __expf(m - mo) + so; m = mo; }
        else if (so > 0.f)   s += so * __expf(mo - m);
    }

    // phase B: lane owns cols lane*4..+3 (head = lane>>3)
    int h2 = lane >> 3;
    float M = __shfl(m, h2);
    float S = __shfl(s, h2);
    float invS = S > 0.f ? 1.f / S : 0.f;
    const int col = lane * 4;
    float a0 = 0.f, a1 = 0.f, a2 = 0.f, a3 = 0.f;
    int i = beg;
    for (; i + 3 < end; i += 4) {
        int s0 = srcS[i], s1 = srcS[i+1], s2 = srcS[i+2], s3 = srcS[i+3];
        float w0 = __expf(eS[(size_t)(i  ) * NH + h2] - M) * invS;
        float w1 = __expf(eS[(size_t)(i+1) * NH + h2] - M) * invS;
        float w2 = __expf(eS[(size_t)(i+2) * NH + h2] - M) * invS;
        float w3 = __expf(eS[(size_t)(i+3) * NH + h2] - M) * invS;
        ushort4 u0 = *reinterpret_cast<const ushort4*>(fs + (size_t)s0 * HD + col);
        ushort4 u1 = *reinterpret_cast<const ushort4*>(fs + (size_t)s1 * HD + col);
        ushort4 u2 = *reinterpret_cast<const ushort4*>(fs + (size_t)s2 * HD + col);
        ushort4 u3 = *reinterpret_cast<const ushort4*>(fs + (size_t)s3 * HD + col);
        a0 = fmaf(w0, bf2f(u0.x), a0); a1 = fmaf(w0, bf2f(u0.y), a1);
        a2 = fmaf(w0, bf2f(u0.z), a2); a3 = fmaf(w0, bf2f(u0.w), a3);
        a0 = fmaf(w1, bf2f(u1.x), a0); a1 = fmaf(w1, bf2f(u1.y), a1);
        a2 = fmaf(w1, bf2f(u1.z), a2); a3 = fmaf(w1, bf2f(u1.w), a3);
        a0 = fmaf(w2, bf2f(u2.x), a0); a1 = fmaf(w2, bf2f(u2.y), a1);
        a2 = fmaf(w2, bf2f(u2.z), a2); a3 = fmaf(w2, bf2f(u2.w), a3);
        a0 = fmaf(w3, bf2f(u3.x), a0); a1 = fmaf(w3, bf2f(u3.y), a1);
        a2 = fmaf(w3, bf2f(u3.z), a2); a3 = fmaf(w3, bf2f(u3.w), a3);
    }
    for (; i < end; ++i) {
        int sn = srcS[i];
        float w = __expf(eS[(size_t)i * NH + h2] - M) * invS;
        ushort4 u = *reinterpret_cast<const ushort4*>(fs + (size_t)sn * HD + col);
        a0 = fmaf(w, bf2f(u.x), a0); a1 = fmaf(w, bf2f(u.y), a1);
        a2 = fmaf(w, bf2f(u.z), a2); a3 = fmaf(w, bf2f(u.w), a3);
    }
    *reinterpret_cast<float4*>(&out[(size_t)node * HD + col]) = make_float4(a0, a1, a2, a3);
}

extern "C" void kernel_launch(void* const* d_in, const int* in_sizes, int n_in,
                              void* d_out, int out_size, void* d_ws, size_t ws_size,
                              hipStream_t stream)
{
    const float* feat   = (const float*)d_in[0];
    const float* e_pro  = (const float*)d_in[1];
    const float* mask   = (const float*)d_in[2];
    const float* W_n    = (const float*)d_in[3];
    const float* attn_l = (const float*)d_in[4];
    const float* attn_r = (const float*)d_in[5];
    const float* attn_m = (const float*)d_in[6];
    const int* src      = (const int*)d_in[7];
    const int* dst      = (const int*)d_in[8];
    float* out = (float*)d_out;

    char* ws = (char*)d_ws;
    size_t o = 0;
    auto alloc = [&](size_t bytes) -> void* {
        void* p = (void*)(ws + o);
        o += (bytes + 255) & ~(size_t)255;
        return p;
    };
    u16* fs     = (u16*)alloc((size_t)NN * HD * 2);
    u16* Wt     = (u16*)alloc((size_t)INDIM * HD * 2);
    u16* el     = (u16*)alloc((size_t)NN * NH * NT * 2);
    u16* er     = (u16*)alloc((size_t)NN * NH * NT * 2);
    float* eS   = (float*)alloc((size_t)NEDGE * NH * 4);
    int* srcS   = (int*)alloc((size_t)NEDGE * 4);
    int* cnt    = (int*)alloc((size_t)NN * 4);
    int* cursor = (int*)alloc((size_t)NN * 4);
    int* offs   = (int*)alloc((size_t)(NN + 1) * 4);
    int* blksum = (int*)alloc(256 * 4);
    (void)ws_size; (void)in_sizes; (void)n_in; (void)out_size;

    dim3 b256(256);
    hipLaunchKernelGGL(wt_kernel, dim3(256), b256, 0, stream, W_n, Wt);
    hipLaunchKernelGGL(gemm_mfma, dim3((NN + 31) / 32), b256, 0, stream, feat, Wt, fs, NN);
    hipLaunchKernelGGL(elr_kernel, dim3((NN + 3) / 4), b256, 0, stream, fs, attn_l, attn_r, el, er, NN);
    hipLaunchKernelGGL(init_kernel, dim3((NN + 255) / 256), b256, 0, stream, cnt, cursor, NN);
    hipLaunchKernelGGL(hist_kernel, dim3((NEDGE + 255) / 256), b256, 0, stream, dst, cnt, NEDGE);
    hipLaunchKernelGGL(scan1_kernel, dim3((NN + 255) / 256), b256, 0, stream, cnt, offs, blksum, NN);
    hipLaunchKernelGGL(scan2_kernel, dim3(1), b256, 0, stream, blksum, (NN + 255) / 256);
    hipLaunchKernelGGL(scan3_kernel, dim3((NN + 255) / 256), b256, 0, stream, offs, blksum, NN, NEDGE);
    hipLaunchKernelGGL(edgefill_kernel, dim3((NEDGE + 31) / 32), b256, 0, stream,
                       e_pro, mask, attn_m, src, dst, el, er, offs, cursor, srcS, eS, NEDGE);
    hipLaunchKernelGGL(agg_kernel, dim3((NN + 3) / 4), b256, 0, stream, offs, srcS, eS, fs, out, NN);
}